// Round 1
// baseline (5441.682 us; speedup 1.0000x reference)
//
#include <hip/hip_runtime.h>
#include <math.h>

#define BB 64
#define TT 512
#define II 128
#define HH 256
#define NCC 10
#define SS (TT+1)
#define TOPK 10
#define EPSF 1e-7f

// d_ws layout (floats):
//  Wp   [256][256][4]  : 262144   packed W_hh:  Wp[kin*1024 + kk*4 + g] = W_hh[(g*256+kk)*256 + kin]
//  Wip  [128][256][4]  : 131072   packed W_ih:  Wip[kin*1024 + kk*4 + g] = W_ih[(g*256+kk)*128 + kin]
//  gx   [B*T][256][4]  : 33554432 gates_x = x@W_ih^T + b_ih + b_hh, packed [row][kk][g]
//  mem  [B][S][H]      : 8404992  memory slots (slot 0 zeroed; slot i+1 = h_out of step i)
//  att  [B][T][H]      : 8388608  attn_c per step
#define OFF_WP   0
#define OFF_WIP  262144
#define OFF_GX   393216
#define OFF_MEM  33947648
#define OFF_ATT  42352640

__device__ __forceinline__ float sigm(float x) { return 1.f / (1.f + expf(-x)); }

__device__ __forceinline__ float wred(float v) {
  #pragma unroll
  for (int off = 32; off; off >>= 1) v += __shfl_xor(v, off, 64);
  return v;
}

// ---------------- prep: pack weights + zero mem slot 0 ----------------
__global__ __launch_bounds__(256) void prep(const float* __restrict__ Whh,
                                            const float* __restrict__ Wih,
                                            float* __restrict__ Wp,
                                            float* __restrict__ Wip,
                                            float* __restrict__ mem) {
  int idx = blockIdx.x * 256 + threadIdx.x;
  if (idx < 262144) {
    int g = idx & 3, kk = (idx >> 2) & 255, kin = idx >> 10;
    Wp[idx] = Whh[(g * 256 + kk) * 256 + kin];
  } else if (idx < 393216) {
    int i2 = idx - 262144;
    int g = i2 & 3, kk = (i2 >> 2) & 255, kin = i2 >> 10;
    Wip[i2] = Wih[(g * 256 + kk) * 128 + kin];
  } else if (idx < 393216 + BB * HH) {
    int i3 = idx - 393216;
    int b = i3 >> 8, k = i3 & 255;
    mem[(size_t)b * SS * HH + k] = 0.f;
  }
}

// ---------------- gxk: gates_x = x @ W_ih^T + b_ih + b_hh ----------------
// grid 2048, block 256. Block covers 16 rows (row = b*T + t), thread kk covers 4 gate-cols.
__global__ __launch_bounds__(256) void gxk(const float* __restrict__ x,
                                           const float* __restrict__ Wip,
                                           const float* __restrict__ bih,
                                           const float* __restrict__ bhh,
                                           float* __restrict__ gx) {
  __shared__ float xs[16][128];
  int tid = threadIdx.x;
  int r0 = blockIdx.x * 16;
  for (int e = tid; e < 16 * 128; e += 256) {
    int r = e >> 7, k = e & 127;
    xs[r][k] = x[(size_t)(r0 + r) * 128 + k];
  }
  __syncthreads();
  int kk = tid;
  float b0 = bih[kk]       + bhh[kk];
  float b1 = bih[256 + kk] + bhh[256 + kk];
  float b2 = bih[512 + kk] + bhh[512 + kk];
  float b3 = bih[768 + kk] + bhh[768 + kk];
  float acc[16][4];
  #pragma unroll
  for (int r = 0; r < 16; ++r) { acc[r][0] = b0; acc[r][1] = b1; acc[r][2] = b2; acc[r][3] = b3; }
  for (int k = 0; k < 128; k += 4) {
    float4 w0 = *(const float4*)(Wip + (size_t)(k + 0) * 1024 + kk * 4);
    float4 w1 = *(const float4*)(Wip + (size_t)(k + 1) * 1024 + kk * 4);
    float4 w2 = *(const float4*)(Wip + (size_t)(k + 2) * 1024 + kk * 4);
    float4 w3 = *(const float4*)(Wip + (size_t)(k + 3) * 1024 + kk * 4);
    #pragma unroll
    for (int r = 0; r < 16; ++r) {
      float4 xv = *(const float4*)&xs[r][k];
      acc[r][0] += xv.x * w0.x + xv.y * w1.x + xv.z * w2.x + xv.w * w3.x;
      acc[r][1] += xv.x * w0.y + xv.y * w1.y + xv.z * w2.y + xv.w * w3.y;
      acc[r][2] += xv.x * w0.z + xv.y * w1.z + xv.z * w2.z + xv.w * w3.z;
      acc[r][3] += xv.x * w0.w + xv.y * w1.w + xv.z * w2.w + xv.w * w3.w;
    }
  }
  #pragma unroll
  for (int r = 0; r < 16; ++r) {
    float4 o = make_float4(acc[r][0], acc[r][1], acc[r][2], acc[r][3]);
    *(float4*)(gx + ((size_t)(r0 + r) * 256 + kk) * 4) = o;
  }
}

// ---------------- recur: per-batch sequential LSTM + sparse attention ----------------
// grid 64 (one block per batch b), block 256 (thread kk owns gate-quad kk / h element kk).
__global__ __launch_bounds__(256, 1) void recur(const float* __restrict__ gx,
                                                const float* __restrict__ Wp,
                                                const float* __restrict__ wt,
                                                float* __restrict__ mem,
                                                float* __restrict__ attns) {
  int b = blockIdx.x, kk = threadIdx.x;
  int lane = kk & 63, wid = kk >> 6;
  __shared__ float h_lds[256];
  __shared__ float ms_lds[12];
  __shared__ float topv[10];
  __shared__ int   topi[10];
  __shared__ float red[4];
  h_lds[kk] = 0.f;
  if (kk < 10) { topv[kk] = (kk == 0) ? 0.f : -3.0e38f; topi[kk] = 0; }
  if (kk == 0) ms_lds[0] = 0.f;
  float c = 0.f;
  float wt1 = wt[kk], wt2 = wt[256 + kk];
  const float* gxb = gx + (size_t)b * TT * 1024;
  float* memb = mem + (size_t)b * SS * HH;
  float* attb = attns + (size_t)b * TT * HH;
  // prefetch state for the top-k branch (set at end of step i for step i+1)
  float pv[9], pm[9], pd = 0.f;
  __syncthreads();

  for (int i = 0; i < TT; ++i) {
    // ---- A: gates = gx[i] + h @ W_hh^T (thread kk -> gates j=g*256+kk, g=0..3)
    float4 a = *(const float4*)(gxb + (size_t)i * 1024 + kk * 4);
    float gi = 0.f, gf = 0.f, gg = 0.f, go = 0.f;
    #pragma unroll 4
    for (int k = 0; k < 256; k += 4) {
      float4 hv = *(const float4*)&h_lds[k];
      float4 w0 = *(const float4*)(Wp + (size_t)(k + 0) * 1024 + kk * 4);
      float4 w1 = *(const float4*)(Wp + (size_t)(k + 1) * 1024 + kk * 4);
      float4 w2 = *(const float4*)(Wp + (size_t)(k + 2) * 1024 + kk * 4);
      float4 w3 = *(const float4*)(Wp + (size_t)(k + 3) * 1024 + kk * 4);
      gi += hv.x * w0.x + hv.y * w1.x + hv.z * w2.x + hv.w * w3.x;
      gf += hv.x * w0.y + hv.y * w1.y + hv.z * w2.y + hv.w * w3.y;
      gg += hv.x * w0.z + hv.y * w1.z + hv.z * w2.z + hv.w * w3.z;
      go += hv.x * w0.w + hv.y * w1.w + hv.z * w2.w + hv.w * w3.w;
    }
    gi += a.x; gf += a.y; gg += a.z; go += a.w;

    // ---- B: LSTM cell
    float cn = sigm(gf) * c + sigm(gi) * tanhf(gg);
    float hn = sigm(go) * tanhf(cn);
    c = cn;

    // ---- C: attention
    float ac = 0.f;
    if (i < TOPK) {
      // early branch: attn = raw scores = hscore + memscore, unnormalized
      float v = wred(tanhf(hn) * wt1);
      if (lane == 0) red[wid] = v;
      __syncthreads();
      float hs = red[0] + red[1] + red[2] + red[3];
      for (int s = 0; s <= i; ++s)
        ac += (hs + ms_lds[s]) * memb[(size_t)s * HH + kk];
    } else {
      // top-k branch: hscore cancels; weights from running top-10 memscores
      float d = pd + EPSF;
      float w[9], sw = 0.f;
      #pragma unroll
      for (int e = 0; e < 9; ++e) { float we = pv[e] - d; we = we > 0.f ? we : 0.f; w[e] = we; sw += we; }
      float inv = 1.f / (sw + EPSF);
      #pragma unroll
      for (int e = 0; e < 9; ++e) ac += w[e] * pm[e];
      ac *= inv;
    }

    // ---- D: output state
    float ho = hn + ac;
    __syncthreads();                    // h_lds / topv / red reads complete
    h_lds[kk] = ho;
    memb[(size_t)(i + 1) * HH + kk] = ho;
    attb[(size_t)i * HH + kk] = ac;

    // ---- E: memscore of new slot + top-10 insert
    float mv = wred(tanhf(ho) * wt2);
    if (lane == 0) red[wid] = mv;
    __syncthreads();
    if (kk == 0) {
      float m = red[0] + red[1] + red[2] + red[3];
      if (i + 1 < 12) ms_lds[i + 1] = m;
      if (m > topv[9]) {
        int p = 9;
        while (p > 0 && m > topv[p - 1]) { topv[p] = topv[p - 1]; topi[p] = topi[p - 1]; --p; }
        topv[p] = m; topi[p] = i + 1;
      }
    }
    __syncthreads();                    // toplist final for step i+1

    // ---- F: prefetch mem rows + list snapshot for next step (latency hides under next GEMV)
    if (i + 1 >= TOPK) {
      pd = topv[9];
      #pragma unroll
      for (int e = 0; e < 9; ++e) {
        pv[e] = topv[e];
        pm[e] = memb[(size_t)topi[e] * HH + kk];
      }
    }
  }
}

// ---------------- fin: out = concat(h_out, attn_c) @ fc_w^T + fc_b ----------------
// grid 2048, block 256. Block covers 16 (b,t) rows; 32 blocks per b (aligned).
__global__ __launch_bounds__(256) void fin(const float* __restrict__ mem,
                                           const float* __restrict__ attns,
                                           const float* __restrict__ fcw,
                                           const float* __restrict__ fcb,
                                           float* __restrict__ out) {
  __shared__ float xin[16][516];
  __shared__ float fw[10][512];
  int tid = threadIdx.x;
  int blk = blockIdx.x;
  int b = blk >> 5;
  int t0 = (blk & 31) << 4;
  for (int e = tid; e < 5120; e += 256) fw[e >> 9][e & 511] = fcw[e];
  const float* memb = mem + (size_t)b * SS * HH;
  const float* attb = attns + (size_t)b * TT * HH;
  for (int e = tid; e < 16 * 512; e += 256) {
    int r = e >> 9, d = e & 511;
    float v = (d < 256) ? memb[(size_t)(t0 + r + 1) * HH + d]
                        : attb[(size_t)(t0 + r) * HH + (d - 256)];
    xin[r][d] = v;
  }
  __syncthreads();
  if (tid < 160) {
    int r = tid & 15, n = tid >> 4;
    float acc = fcb[n];
    for (int d = 0; d < 512; ++d) acc += xin[r][d] * fw[n][d];
    out[((size_t)b * TT + t0 + r) * NCC + n] = acc;
  }
}

extern "C" void kernel_launch(void* const* d_in, const int* in_sizes, int n_in,
                              void* d_out, int out_size, void* d_ws, size_t ws_size,
                              hipStream_t stream) {
  const float* x   = (const float*)d_in[0];
  const float* Wih = (const float*)d_in[1];
  const float* Whh = (const float*)d_in[2];
  const float* bih = (const float*)d_in[3];
  const float* bhh = (const float*)d_in[4];
  const float* wt  = (const float*)d_in[5];
  const float* fcw = (const float*)d_in[6];
  const float* fcb = (const float*)d_in[7];
  float* ws  = (float*)d_ws;
  float* Wp  = ws + OFF_WP;
  float* Wip = ws + OFF_WIP;
  float* gx  = ws + OFF_GX;
  float* mem = ws + OFF_MEM;
  float* att = ws + OFF_ATT;
  float* out = (float*)d_out;

  prep<<<1600, 256, 0, stream>>>(Whh, Wih, Wp, Wip, mem);
  gxk<<<2048, 256, 0, stream>>>(x, Wip, bih, bhh, gx);
  recur<<<64, 256, 0, stream>>>(gx, Wp, wt, mem, att);
  fin<<<2048, 256, 0, stream>>>(mem, att, fcw, fcb, out);
}

// Round 3
// 4030.218 us; speedup vs baseline: 1.3502x; 1.3502x over previous
//
#include <hip/hip_runtime.h>
#include <math.h>

#define BB 64
#define TT 512
#define II 128
#define HH 256
#define NCC 10
#define SS (TT+1)
#define TOPK 10
#define EPSF 1e-7f

// d_ws layout (floats):
//  Wpk  [4][512][32][4] : 262144   W_hh packed for register residency (quarter q, thread t, chunk c)
//  Wip  [128][256][4]   : 131072   packed W_ih
//  gx   [B*T][256][4]   : 33554432 gates_x = x@W_ih^T + b_ih + b_hh
//  mem  [B][S][H]       : 8404992
//  att  [B][T][H]       : 8388608
//  xh   [2][B][H]       : 32768    h_out exchange (double-buffered by step parity)
//  xh2  [B][H]          : 16384    h_new exchange (early steps only)
//  bar  [B*16] ints     : 1024     per-batch monotonic barrier counters
#define OFF_WPK  0
#define OFF_WIP  262144
#define OFF_GX   393216
#define OFF_MEM  33947648
#define OFF_ATT  42352640
#define OFF_XH   50741248
#define OFF_XH2  50774016
#define OFF_BAR  50790400

__device__ __forceinline__ float sigm(float x) { return 1.f / (1.f + expf(-x)); }

__device__ __forceinline__ float wred(float v) {
  #pragma unroll
  for (int off = 32; off; off >>= 1) v += __shfl_xor(v, off, 64);
  return v;
}

// ---------------- prep: pack weights + zero mem slot 0 + zero barriers ----------------
__global__ __launch_bounds__(256) void prep(const float* __restrict__ Whh,
                                            const float* __restrict__ Wih,
                                            float* __restrict__ Wpk,
                                            float* __restrict__ Wip,
                                            float* __restrict__ mem,
                                            int* __restrict__ bar) {
  int idx = blockIdx.x * 256 + threadIdx.x;
  if (idx < 262144) {
    // idx = q*65536 + t*128 + c*4 + e ; t=(rq<<3)|ks ; c=(rr<<3)|kc
    int e  = idx & 3;
    int c7 = (idx >> 2) & 31;
    int t  = (idx >> 7) & 511;
    int q  = idx >> 16;
    int rr = c7 >> 3, kc = c7 & 7;
    int rq = t >> 3,  ks = t & 7;
    int r  = rq * 4 + rr;          // local row 0..255 ; r = g*64 + uu
    int g  = r >> 6, u2 = r & 63;  // gate, unit-within-quarter
    int j  = g * 256 + q * 64 + u2;
    int k  = ks * 32 + kc * 4 + e;
    Wpk[idx] = Whh[j * 256 + k];
  } else if (idx < 393216) {
    int i2 = idx - 262144;
    int g = i2 & 3, kk = (i2 >> 2) & 255, kin = i2 >> 10;
    Wip[i2] = Wih[(g * 256 + kk) * 128 + kin];
  } else if (idx < 409600) {
    int i3 = idx - 393216;
    int b = i3 >> 8, k = i3 & 255;
    mem[(size_t)b * SS * HH + k] = 0.f;
  } else if (idx < 410624) {
    bar[idx - 409600] = 0;
  }
}

// ---------------- gxk: gates_x = x @ W_ih^T + b_ih + b_hh ----------------
__global__ __launch_bounds__(256) void gxk(const float* __restrict__ x,
                                           const float* __restrict__ Wip,
                                           const float* __restrict__ bih,
                                           const float* __restrict__ bhh,
                                           float* __restrict__ gx) {
  __shared__ float xs[16][128];
  int tid = threadIdx.x;
  int r0 = blockIdx.x * 16;
  for (int e = tid; e < 16 * 128; e += 256) {
    int r = e >> 7, k = e & 127;
    xs[r][k] = x[(size_t)(r0 + r) * 128 + k];
  }
  __syncthreads();
  int kk = tid;
  float b0 = bih[kk]       + bhh[kk];
  float b1 = bih[256 + kk] + bhh[256 + kk];
  float b2 = bih[512 + kk] + bhh[512 + kk];
  float b3 = bih[768 + kk] + bhh[768 + kk];
  float acc[16][4];
  #pragma unroll
  for (int r = 0; r < 16; ++r) { acc[r][0] = b0; acc[r][1] = b1; acc[r][2] = b2; acc[r][3] = b3; }
  for (int k = 0; k < 128; k += 4) {
    float4 w0 = *(const float4*)(Wip + (size_t)(k + 0) * 1024 + kk * 4);
    float4 w1 = *(const float4*)(Wip + (size_t)(k + 1) * 1024 + kk * 4);
    float4 w2 = *(const float4*)(Wip + (size_t)(k + 2) * 1024 + kk * 4);
    float4 w3 = *(const float4*)(Wip + (size_t)(k + 3) * 1024 + kk * 4);
    #pragma unroll
    for (int r = 0; r < 16; ++r) {
      float4 xv = *(const float4*)&xs[r][k];
      acc[r][0] += xv.x * w0.x + xv.y * w1.x + xv.z * w2.x + xv.w * w3.x;
      acc[r][1] += xv.x * w0.y + xv.y * w1.y + xv.z * w2.y + xv.w * w3.y;
      acc[r][2] += xv.x * w0.z + xv.y * w1.z + xv.z * w2.z + xv.w * w3.z;
      acc[r][3] += xv.x * w0.w + xv.y * w1.w + xv.z * w2.w + xv.w * w3.w;
    }
  }
  #pragma unroll
  for (int r = 0; r < 16; ++r) {
    float4 o = make_float4(acc[r][0], acc[r][1], acc[r][2], acc[r][3]);
    *(float4*)(gx + ((size_t)(r0 + r) * 256 + kk) * 4) = o;
  }
}

// ---------------- recur: 4 blocks per batch, W_hh quarter register-resident ----------------
// grid 256 = quarter q (bid>>6) x batch b (bid&63)  [same-XCD placement: 64%8==0].
// block 512 threads; thread t: rq=t>>3 (row-quad), ks=t&7 (k-slice of 32).
__global__ __launch_bounds__(512, 2) void recur(const float* __restrict__ gxp,
                                                const float* __restrict__ Wpk,
                                                const float* __restrict__ wt,
                                                float* __restrict__ mem,
                                                float* __restrict__ attns,
                                                float* __restrict__ xh,
                                                float* __restrict__ xh2,
                                                int* __restrict__ bar) {
  const int bid = blockIdx.x;
  const int q = bid >> 6;
  const int b = bid & 63;
  const int t = threadIdx.x;
  const int rq = t >> 3, ks = t & 7;

  __shared__ float h_s[288];     // padded: element k lives at k + (k>>5)*4
  __shared__ float g_s[256];     // gates for this block's 256 rows (r = g*64+uu)
  __shared__ float ms[12];       // memscores of early slots
  __shared__ float topv[10];
  __shared__ int   topi[10];

  // --- register-resident W quarter: 32 float4 per thread ---
  float4 wr[32];
  {
    const float4* wsrc = (const float4*)Wpk + ((size_t)q * 512 + t) * 32;
    #pragma unroll
    for (int c = 0; c < 32; ++c) wr[c] = wsrc[c];
  }

  // --- init ---
  for (int k = t; k < 288; k += 512) h_s[k] = 0.f;
  if (t < 10) { topv[t] = (t == 0) ? 0.f : -3.0e38f; topi[t] = 0; }
  if (t == 0) ms[0] = 0.f;

  const int uu  = t;             // unit-within-quarter, valid for t<64
  const int col = q * 64 + uu;   // global h column, valid for t<64
  float c_st = 0.f;
  float w1x=0,w1y=0,w1z=0,w1w=0, w2x=0,w2y=0,w2z=0,w2w=0;
  const float* gxb = gxp;
  float* memc = mem;
  float* attc = attns;
  float4 pgx = make_float4(0.f,0.f,0.f,0.f);
  float pm[9];
  #pragma unroll
  for (int e = 0; e < 9; ++e) pm[e] = 0.f;
  if (t < 64) {
    float4 v1 = *(const float4*)&wt[uu * 4];
    float4 v2 = *(const float4*)&wt[256 + uu * 4];
    w1x=v1.x; w1y=v1.y; w1z=v1.z; w1w=v1.w;
    w2x=v2.x; w2y=v2.y; w2z=v2.z; w2w=v2.w;
    gxb  = gxp + (size_t)b * TT * 1024 + (size_t)col * 4;
    memc = mem + (size_t)b * SS * HH + col;
    attc = attns + (size_t)b * TT * HH + col;
    pgx = *(const float4*)gxb;   // prefetch gx row 0
  }
  int* bp = bar + b * 16;
  int bcnt = 0;
  __syncthreads();

  for (int i = 0; i < TT; ++i) {
    // ---- A: GEMV partials over this thread's k-slice ----
    float a0 = 0.f, a1 = 0.f, a2 = 0.f, a3 = 0.f;
    #pragma unroll
    for (int kc = 0; kc < 8; ++kc) {
      float4 h4 = *(const float4*)&h_s[ks * 36 + kc * 4];
      a0 += h4.x * wr[0*8+kc].x + h4.y * wr[0*8+kc].y + h4.z * wr[0*8+kc].z + h4.w * wr[0*8+kc].w;
      a1 += h4.x * wr[1*8+kc].x + h4.y * wr[1*8+kc].y + h4.z * wr[1*8+kc].z + h4.w * wr[1*8+kc].w;
      a2 += h4.x * wr[2*8+kc].x + h4.y * wr[2*8+kc].y + h4.z * wr[2*8+kc].z + h4.w * wr[2*8+kc].w;
      a3 += h4.x * wr[3*8+kc].x + h4.y * wr[3*8+kc].y + h4.z * wr[3*8+kc].z + h4.w * wr[3*8+kc].w;
    }
    // reduce the 8 k-slices (adjacent lanes share rq)
    #pragma unroll
    for (int off = 1; off < 8; off <<= 1) {
      a0 += __shfl_xor(a0, off, 64);
      a1 += __shfl_xor(a1, off, 64);
      a2 += __shfl_xor(a2, off, 64);
      a3 += __shfl_xor(a3, off, 64);
    }
    if (ks == 0) *(float4*)&g_s[rq * 4] = make_float4(a0, a1, a2, a3);
    __syncthreads();

    // ---- B: LSTM cell (wave 0 only) ----
    float hn = 0.f, ac = 0.f;
    if (t < 64) {
      float gi = g_s[uu]        + pgx.x;
      float gf = g_s[64 + uu]   + pgx.y;
      float gg = g_s[128 + uu]  + pgx.z;
      float go = g_s[192 + uu]  + pgx.w;
      float cn = sigm(gf) * c_st + sigm(gi) * tanhf(gg);
      hn = sigm(go) * tanhf(cn);
      c_st = cn;
    }

    // ---- C: attention ----
    if (i < TOPK) {
      if (t < 64)
        __hip_atomic_store(&xh2[b * 256 + col], hn, __ATOMIC_RELAXED, __HIP_MEMORY_SCOPE_AGENT);
      // barrier #1 (h_new exchange)
      __syncthreads();
      ++bcnt;
      if (t == 0) {
        __hip_atomic_fetch_add(bp, 1, __ATOMIC_ACQ_REL, __HIP_MEMORY_SCOPE_AGENT);
        while (__hip_atomic_load(bp, __ATOMIC_ACQUIRE, __HIP_MEMORY_SCOPE_AGENT) < bcnt * 4)
          __builtin_amdgcn_s_sleep(1);
      }
      __syncthreads();
      if (t < 64) {
        float v0 = __hip_atomic_load(&xh2[b*256 + uu*4 + 0], __ATOMIC_RELAXED, __HIP_MEMORY_SCOPE_AGENT);
        float v1 = __hip_atomic_load(&xh2[b*256 + uu*4 + 1], __ATOMIC_RELAXED, __HIP_MEMORY_SCOPE_AGENT);
        float v2 = __hip_atomic_load(&xh2[b*256 + uu*4 + 2], __ATOMIC_RELAXED, __HIP_MEMORY_SCOPE_AGENT);
        float v3 = __hip_atomic_load(&xh2[b*256 + uu*4 + 3], __ATOMIC_RELAXED, __HIP_MEMORY_SCOPE_AGENT);
        float p = tanhf(v0)*w1x + tanhf(v1)*w1y + tanhf(v2)*w1z + tanhf(v3)*w1w;
        p = wred(p);               // hscore, in all wave-0 lanes
        for (int s = 0; s <= i; ++s)
          ac += (p + ms[s]) * memc[(size_t)s * HH];
      }
    } else {
      if (t < 64) {
        float d = topv[9] + EPSF;
        float sw = 0.f, s0 = 0.f;
        #pragma unroll
        for (int e = 0; e < 9; ++e) {
          float we = topv[e] - d; we = we > 0.f ? we : 0.f;
          sw += we; s0 += we * pm[e];
        }
        ac = s0 / (sw + EPSF);
      }
    }

    // ---- D: h_out, stores, exchange ----
    if (t < 64) {
      float ho = hn + ac;
      __hip_atomic_store(&xh[(i & 1) * 16384 + b * 256 + col], ho,
                         __ATOMIC_RELAXED, __HIP_MEMORY_SCOPE_AGENT);
      memc[(size_t)(i + 1) * HH] = ho;
      attc[(size_t)i * HH] = ac;
    }
    // common barrier
    __syncthreads();
    ++bcnt;
    if (t == 0) {
      __hip_atomic_fetch_add(bp, 1, __ATOMIC_ACQ_REL, __HIP_MEMORY_SCOPE_AGENT);
      while (__hip_atomic_load(bp, __ATOMIC_ACQUIRE, __HIP_MEMORY_SCOPE_AGENT) < bcnt * 4)
        __builtin_amdgcn_s_sleep(1);
    }
    __syncthreads();

    // ---- E: reload full h_out into LDS ----
    if (t < 256) {
      float v = __hip_atomic_load(&xh[(i & 1) * 16384 + b * 256 + t],
                                  __ATOMIC_RELAXED, __HIP_MEMORY_SCOPE_AGENT);
      h_s[t + ((t >> 5) << 2)] = v;
    }
    __syncthreads();

    // ---- F: memscore of new slot + replica top-10 insert ----
    if (t < 64) {
      int k0 = t * 4, w0 = k0 + ((k0 >> 5) << 2);
      float4 hv = *(const float4*)&h_s[w0];
      float m = tanhf(hv.x)*w2x + tanhf(hv.y)*w2y + tanhf(hv.z)*w2z + tanhf(hv.w)*w2w;
      m = wred(m);
      if (t == 0) {
        if (i + 1 < 12) ms[i + 1] = m;
        if (m > topv[9]) {
          int p9 = 9;
          while (p9 > 0 && m > topv[p9 - 1]) {
            topv[p9] = topv[p9 - 1]; topi[p9] = topi[p9 - 1]; --p9;
          }
          topv[p9] = m; topi[p9] = i + 1;
        }
      }
    }
    __syncthreads();

    // ---- G: prefetch for next step ----
    if (t < 64) {
      if (i + 1 >= TOPK) {
        #pragma unroll
        for (int e = 0; e < 9; ++e) pm[e] = memc[(size_t)topi[e] * HH];
      }
      int ip = (i + 1 < TT) ? i + 1 : i;
      pgx = *(const float4*)(gxb + (size_t)ip * 1024);
    }
  }
}

// ---------------- fin: out = concat(h_out, attn_c) @ fc_w^T + fc_b ----------------
__global__ __launch_bounds__(256) void fin(const float* __restrict__ mem,
                                           const float* __restrict__ attns,
                                           const float* __restrict__ fcw,
                                           const float* __restrict__ fcb,
                                           float* __restrict__ out) {
  __shared__ float xin[16][516];
  __shared__ float fw[10][512];
  int tid = threadIdx.x;
  int blk = blockIdx.x;
  int b = blk >> 5;
  int t0 = (blk & 31) << 4;
  for (int e = tid; e < 5120; e += 256) fw[e >> 9][e & 511] = fcw[e];
  const float* memb = mem + (size_t)b * SS * HH;
  const float* attb = attns + (size_t)b * TT * HH;
  for (int e = tid; e < 16 * 512; e += 256) {
    int r = e >> 9, d = e & 511;
    float v = (d < 256) ? memb[(size_t)(t0 + r + 1) * HH + d]
                        : attb[(size_t)(t0 + r) * HH + (d - 256)];
    xin[r][d] = v;
  }
  __syncthreads();
  if (tid < 160) {
    int r = tid & 15, n = tid >> 4;
    float acc = fcb[n];
    for (int d = 0; d < 512; ++d) acc += xin[r][d] * fw[n][d];
    out[((size_t)b * TT + t0 + r) * NCC + n] = acc;
  }
}

extern "C" void kernel_launch(void* const* d_in, const int* in_sizes, int n_in,
                              void* d_out, int out_size, void* d_ws, size_t ws_size,
                              hipStream_t stream) {
  const float* x   = (const float*)d_in[0];
  const float* Wih = (const float*)d_in[1];
  const float* Whh = (const float*)d_in[2];
  const float* bih = (const float*)d_in[3];
  const float* bhh = (const float*)d_in[4];
  const float* wt  = (const float*)d_in[5];
  const float* fcw = (const float*)d_in[6];
  const float* fcb = (const float*)d_in[7];
  float* ws   = (float*)d_ws;
  float* Wpk  = ws + OFF_WPK;
  float* Wip  = ws + OFF_WIP;
  float* gx   = ws + OFF_GX;
  float* mem  = ws + OFF_MEM;
  float* att  = ws + OFF_ATT;
  float* xh   = ws + OFF_XH;
  float* xh2  = ws + OFF_XH2;
  int*   bar  = (int*)(ws + OFF_BAR);
  float* out  = (float*)d_out;

  prep<<<1604, 256, 0, stream>>>(Whh, Wih, Wpk, Wip, mem, bar);
  gxk<<<2048, 256, 0, stream>>>(x, Wip, bih, bhh, gx);
  recur<<<256, 512, 0, stream>>>(gx, Wpk, wt, mem, att, xh, xh2, bar);
  fin<<<2048, 256, 0, stream>>>(mem, att, fcw, fcb, out);
}